// Round 4
// baseline (89.178 us; speedup 1.0000x reference)
//
#include <hip/hip_runtime.h>

// Problem constants (from reference)
#define B        8192
#define N_IN     8
#define N_MFS    4
#define N_RULES  2048

#define THREADS  256
#define NB       4            // batches per block (R4: 8->4 for 32 waves/CU)
#define LUT_W    101          // words per batch pair-LUT (100 used + 1 pad)

// One kernel. Per block: NB batches x all 2048 rules.
//  - Each thread packs its own 8 rules (2 passes x 4) from mf into 32
//    register-resident LDS WORD offsets (p*25 + a*5 + b, a/b=4 -> masked).
//  - LDS holds only the per-batch pair-product LUTs (NB*101 words).
//  - Gathers hit a 25-consecutive-word region -> same-bank implies same-word
//    -> broadcast, conflict-free.
//  - 4 rules/thread -> float4 coalesced stores (1 KB/wave-instr).
//  - NB=4: 2048 blocks = 8 blocks/CU = 32 waves/CU (max occupancy) to hide
//    the ds_read -> mul -> store dependency chains.
__global__ __launch_bounds__(THREADS) void fire_kernel(
        const float* __restrict__ x,
        const int*   __restrict__ mf,
        float* __restrict__ out)
{
    __shared__ float slut[NB * LUT_W];

    const int tid = threadIdx.x;
    const int b0  = blockIdx.x * NB;

    // ---- Pack this thread's 8 rules into 32 register-resident word offsets.
    int woff[2][4][4];
#pragma unroll
    for (int pass = 0; pass < 2; ++pass) {
#pragma unroll
        for (int j = 0; j < 4; ++j) {
            const int r = pass * (THREADS * 4) + tid * 4 + j;
            const int4* mr = (const int4*)(mf + r * N_IN);
            const int4 lo = mr[0];
            const int4 hi = mr[1];
            const int idx[8] = {lo.x, lo.y, lo.z, lo.w, hi.x, hi.y, hi.z, hi.w};
#pragma unroll
            for (int p = 0; p < 4; ++p) {
                const int a = idx[2*p]   < 0 ? 4 : idx[2*p];
                const int b = idx[2*p+1] < 0 ? 4 : idx[2*p+1];
                woff[pass][j][p] = p * 25 + a * 5 + b;
            }
        }
    }

    // ---- Build pair-product LUTs: slut[bl*101 + p*25 + a*5 + b] = va*vb.
    for (int e = tid; e < NB * 100; e += THREADS) {
        const int bl   = e / 100;
        const int rest = e - bl * 100;
        const int p    = rest / 25;
        const int c    = rest - p * 25;
        const int a    = c / 5;
        const int bb   = c - a * 5;
        const float* xb = x + (size_t)(b0 + bl) * (N_IN * N_MFS);
        const float va = (a  < 4) ? xb[(2*p)   * N_MFS + a ] : 1.0f;
        const float vb = (bb < 4) ? xb[(2*p+1) * N_MFS + bb] : 1.0f;
        slut[bl * LUT_W + rest] = va * vb;
    }
    __syncthreads();

    // ---- Main loop: ds_read_b32 with imm batch offsets, float4 stores.
#pragma unroll
    for (int bl = 0; bl < NB; ++bl) {
#pragma unroll
        for (int pass = 0; pass < 2; ++pass) {
            float4 res;
            float* o = out + (size_t)(b0 + bl) * N_RULES + pass * (THREADS * 4) + tid * 4;
#pragma unroll
            for (int j = 0; j < 4; ++j) {
                const float v0 = slut[bl * LUT_W + woff[pass][j][0]];
                const float v1 = slut[bl * LUT_W + woff[pass][j][1]];
                const float v2 = slut[bl * LUT_W + woff[pass][j][2]];
                const float v3 = slut[bl * LUT_W + woff[pass][j][3]];
                const float r  = (v0 * v1) * (v2 * v3);
                if (j == 0) res.x = r;
                else if (j == 1) res.y = r;
                else if (j == 2) res.z = r;
                else res.w = r;
            }
            *(float4*)o = res;
        }
    }
}

extern "C" void kernel_launch(void* const* d_in, const int* in_sizes, int n_in,
                              void* d_out, int out_size, void* d_ws, size_t ws_size,
                              hipStream_t stream) {
    const float* x  = (const float*)d_in[0];   // (B, N_IN, N_MFS) fp32
    const int*   mf = (const int*)d_in[1];     // (N_RULES, N_IN) int32
    float* out = (float*)d_out;                // (B, N_RULES) fp32
    (void)d_ws; (void)ws_size;

    fire_kernel<<<B / NB, THREADS, 0, stream>>>(x, mf, out);
}

// Round 6
// 84.316 us; speedup vs baseline: 1.0577x; 1.0577x over previous
//
#include <hip/hip_runtime.h>

// Problem constants (from reference)
#define B        8192
#define N_IN     8
#define N_MFS    4
#define N_RULES  2048

#define THREADS  256
#define NB       16           // batches per block (R6: amortize per-block pack)
#define LUT_W    101          // words per batch pair-LUT (100 used + 1 pad)

typedef float vfloat4 __attribute__((ext_vector_type(4)));  // native vec for NT store

// One kernel. Per block: NB batches x all 2048 rules.
//  - Each thread packs its own 8 rules (2 passes x 4) from mf into 32
//    register-resident LDS WORD offsets (p*25 + a*5 + b, a/b=4 -> masked).
//  - LDS holds only the per-batch pair-product LUTs (NB*101 words).
//  - Gathers hit a 25-consecutive-word region -> same-bank implies same-word
//    -> broadcast, conflict-free (confirmed SQ_LDS_BANK_CONFLICT == 0).
//  - 4 rules/thread -> 16B nontemporal stores (out is never re-read).
//  - NB=16: 512 blocks halves per-block mf re-read (32 MB total) and
//    rule-pack VALU vs NB=8. NB 8->4 regressed 4.8us (R4) -> amortization
//    dominates occupancy for this kernel.
__global__ __launch_bounds__(THREADS) void fire_kernel(
        const float* __restrict__ x,
        const int*   __restrict__ mf,
        float* __restrict__ out)
{
    __shared__ float slut[NB * LUT_W];

    const int tid = threadIdx.x;
    const int b0  = blockIdx.x * NB;

    // ---- Pack this thread's 8 rules into 32 register-resident word offsets.
    int woff[2][4][4];
#pragma unroll
    for (int pass = 0; pass < 2; ++pass) {
#pragma unroll
        for (int j = 0; j < 4; ++j) {
            const int r = pass * (THREADS * 4) + tid * 4 + j;
            const int4* mr = (const int4*)(mf + r * N_IN);
            const int4 lo = mr[0];
            const int4 hi = mr[1];
            const int idx[8] = {lo.x, lo.y, lo.z, lo.w, hi.x, hi.y, hi.z, hi.w};
#pragma unroll
            for (int p = 0; p < 4; ++p) {
                const int a = idx[2*p]   < 0 ? 4 : idx[2*p];
                const int b = idx[2*p+1] < 0 ? 4 : idx[2*p+1];
                woff[pass][j][p] = p * 25 + a * 5 + b;
            }
        }
    }

    // ---- Build pair-product LUTs: slut[bl*101 + p*25 + a*5 + b] = va*vb.
    for (int e = tid; e < NB * 100; e += THREADS) {
        const int bl   = e / 100;
        const int rest = e - bl * 100;
        const int p    = rest / 25;
        const int c    = rest - p * 25;
        const int a    = c / 5;
        const int bb   = c - a * 5;
        const float* xb = x + (size_t)(b0 + bl) * (N_IN * N_MFS);
        const float va = (a  < 4) ? xb[(2*p)   * N_MFS + a ] : 1.0f;
        const float vb = (bb < 4) ? xb[(2*p+1) * N_MFS + bb] : 1.0f;
        slut[bl * LUT_W + rest] = va * vb;
    }
    __syncthreads();

    // ---- Main loop: ds_read_b32 with imm batch offsets, 16B NT stores.
#pragma unroll
    for (int bl = 0; bl < NB; ++bl) {
#pragma unroll
        for (int pass = 0; pass < 2; ++pass) {
            vfloat4 res;
            float* o = out + (size_t)(b0 + bl) * N_RULES + pass * (THREADS * 4) + tid * 4;
#pragma unroll
            for (int j = 0; j < 4; ++j) {
                const float v0 = slut[bl * LUT_W + woff[pass][j][0]];
                const float v1 = slut[bl * LUT_W + woff[pass][j][1]];
                const float v2 = slut[bl * LUT_W + woff[pass][j][2]];
                const float v3 = slut[bl * LUT_W + woff[pass][j][3]];
                res[j] = (v0 * v1) * (v2 * v3);
            }
            __builtin_nontemporal_store(res, (vfloat4*)o);
        }
    }
}

extern "C" void kernel_launch(void* const* d_in, const int* in_sizes, int n_in,
                              void* d_out, int out_size, void* d_ws, size_t ws_size,
                              hipStream_t stream) {
    const float* x  = (const float*)d_in[0];   // (B, N_IN, N_MFS) fp32
    const int*   mf = (const int*)d_in[1];     // (N_RULES, N_IN) int32
    float* out = (float*)d_out;                // (B, N_RULES) fp32
    (void)d_ws; (void)ws_size;

    fire_kernel<<<B / NB, THREADS, 0, stream>>>(x, mf, out);
}